// Round 11
// baseline (2165.766 us; speedup 1.0000x reference)
//
#include <hip/hip_runtime.h>
#include <hip/hip_bf16.h>
#include <hip/hip_fp16.h>
#include <math.h>

#define B_ 2
#define T_ 2048
#define C_ 1024
#define H_ 16
#define D_ 64
#define CS_ 64
#define NC_ 32
#define NS_ 5
#define IST2 72   // fp16 row stride (64 elems + 8 pad; 16B-aligned rows)

typedef __attribute__((ext_vector_type(8))) _Float16 f16x8;
typedef __attribute__((ext_vector_type(4))) float f32x4;

// ---------------------------------------------------------------------------
// convert f32 -> fp16 buffer (for fp16 MFMA GEMM operands)
// ---------------------------------------------------------------------------
__global__ __launch_bounds__(256) void split16_kernel(const float* __restrict__ src,
                                                      _Float16* __restrict__ dst,
                                                      int n) {
    int i = (blockIdx.x * 256 + threadIdx.x) * 8;
    if (i >= n) return;
    float4 a = *(const float4*)&src[i];
    float4 b = *(const float4*)&src[i + 4];
    union { _Float16 h[8]; uint4 u; } o;
    o.h[0] = (_Float16)a.x; o.h[1] = (_Float16)a.y;
    o.h[2] = (_Float16)a.z; o.h[3] = (_Float16)a.w;
    o.h[4] = (_Float16)b.x; o.h[5] = (_Float16)b.y;
    o.h[6] = (_Float16)b.z; o.h[7] = (_Float16)b.w;
    *(uint4*)&dst[i] = o.u;
}

// ---------------------------------------------------------------------------
// FP16 MFMA GEMM: out[m,n] = sum_k A[m,k]*B[n,k]
// ---------------------------------------------------------------------------
__global__ __launch_bounds__(256, 1) void gemm16(const _Float16* __restrict__ A,
                                                 const _Float16* __restrict__ Bm,
                                                 float* __restrict__ out) {
    __shared__ __align__(16) _Float16 sA[128 * 72];
    __shared__ __align__(16) _Float16 sB[128 * 72];
    int tid = threadIdx.x;
    int m0 = blockIdx.y * 128, n0 = blockIdx.x * 128;
    int w = tid >> 6, lane = tid & 63, q = lane >> 4, c = lane & 15;
    int mq = (w >> 1) * 64, nq = (w & 1) * 64;
    f32x4 acc[4][4];
    #pragma unroll
    for (int i = 0; i < 4; i++)
        #pragma unroll
        for (int j = 0; j < 4; j++) acc[i][j] = (f32x4){0.f, 0.f, 0.f, 0.f};
    int lrow = tid >> 2, lseg = (tid & 3) * 16;
    for (int kt = 0; kt < C_; kt += 64) {
        #pragma unroll
        for (int rr = 0; rr < 2; rr++) {
            int row = lrow + rr * 64;
            const size_t ga = (size_t)(m0 + row) * C_ + kt + lseg;
            const size_t gb = (size_t)(n0 + row) * C_ + kt + lseg;
            f16x8 va0 = *(const f16x8*)&A[ga];
            f16x8 va1 = *(const f16x8*)&A[ga + 8];
            f16x8 vb0 = *(const f16x8*)&Bm[gb];
            f16x8 vb1 = *(const f16x8*)&Bm[gb + 8];
            *(f16x8*)&sA[row * 72 + lseg] = va0;
            *(f16x8*)&sA[row * 72 + lseg + 8] = va1;
            *(f16x8*)&sB[row * 72 + lseg] = vb0;
            *(f16x8*)&sB[row * 72 + lseg + 8] = vb1;
        }
        __syncthreads();
        #pragma unroll
        for (int t = 0; t < 2; t++) {
            f16x8 af[4], bfr[4];
            #pragma unroll
            for (int i = 0; i < 4; i++)
                af[i] = *(const f16x8*)&sA[(mq + 16 * i + c) * 72 + t * 32 + q * 8];
            #pragma unroll
            for (int j = 0; j < 4; j++)
                bfr[j] = *(const f16x8*)&sB[(nq + 16 * j + c) * 72 + t * 32 + q * 8];
            #pragma unroll
            for (int i = 0; i < 4; i++)
                #pragma unroll
                for (int j = 0; j < 4; j++)
                    acc[i][j] = __builtin_amdgcn_mfma_f32_16x16x32_f16(af[i], bfr[j], acc[i][j], 0, 0, 0);
        }
        __syncthreads();
    }
    #pragma unroll
    for (int i = 0; i < 4; i++)
        #pragma unroll
        for (int j = 0; j < 4; j++)
            #pragma unroll
            for (int r = 0; r < 4; r++)
                out[(size_t)(m0 + mq + 16 * i + 4 * q + r) * C_ + n0 + nq + 16 * j + c] = acc[i][j][r];
}

// ---------------------------------------------------------------------------
// Gate projections via fp16 MFMA: logits = xH (4096xC) . WgH (64xC)^T,
// sigmoid, scatter to gates[g][bt][h] layout (n = g*16+h).
// ---------------------------------------------------------------------------
__global__ __launch_bounds__(256) void gates16(const _Float16* __restrict__ xH,
                                               const _Float16* __restrict__ WgH,
                                               float* __restrict__ gates) {
    __shared__ __align__(16) _Float16 sX[64 * 72];
    __shared__ __align__(16) _Float16 sW[64 * 72];
    int tid = threadIdx.x;
    int m0 = blockIdx.x * 64;
    int w = tid >> 6, lane = tid & 63, q = lane >> 4, c = lane & 15;
    int ar0 = (w >> 1) * 32, br0 = (w & 1) * 32;
    f32x4 acc[2][2];
    #pragma unroll
    for (int i = 0; i < 2; i++)
        #pragma unroll
        for (int j = 0; j < 2; j++) acc[i][j] = (f32x4){0.f, 0.f, 0.f, 0.f};
    int lrow = tid >> 2, lseg = (tid & 3) * 16;
    for (int kt = 0; kt < C_; kt += 64) {
        *(f16x8*)&sX[lrow * 72 + lseg]     = *(const f16x8*)&xH[(size_t)(m0 + lrow) * C_ + kt + lseg];
        *(f16x8*)&sX[lrow * 72 + lseg + 8] = *(const f16x8*)&xH[(size_t)(m0 + lrow) * C_ + kt + lseg + 8];
        *(f16x8*)&sW[lrow * 72 + lseg]     = *(const f16x8*)&WgH[(size_t)lrow * C_ + kt + lseg];
        *(f16x8*)&sW[lrow * 72 + lseg + 8] = *(const f16x8*)&WgH[(size_t)lrow * C_ + kt + lseg + 8];
        __syncthreads();
        #pragma unroll
        for (int t = 0; t < 2; t++) {
            f16x8 af[2], bf[2];
            #pragma unroll
            for (int i = 0; i < 2; i++)
                af[i] = *(const f16x8*)&sX[(ar0 + 16 * i + c) * 72 + t * 32 + q * 8];
            #pragma unroll
            for (int j = 0; j < 2; j++)
                bf[j] = *(const f16x8*)&sW[(br0 + 16 * j + c) * 72 + t * 32 + q * 8];
            #pragma unroll
            for (int i = 0; i < 2; i++)
                #pragma unroll
                for (int j = 0; j < 2; j++)
                    acc[i][j] = __builtin_amdgcn_mfma_f32_16x16x32_f16(af[i], bf[j], acc[i][j], 0, 0, 0);
        }
        __syncthreads();
    }
    #pragma unroll
    for (int i = 0; i < 2; i++)
        #pragma unroll
        for (int j = 0; j < 2; j++)
            #pragma unroll
            for (int r = 0; r < 4; r++) {
                int bt = m0 + ar0 + 16 * i + 4 * q + r;
                int n  = br0 + 16 * j + c;
                float v = acc[i][j][r];
                gates[(size_t)(n >> 4) * (B_ * T_ * H_) + (size_t)bt * H_ + (n & 15)] =
                    1.f / (1.f + __expf(-v));
            }
}

// ---------------------------------------------------------------------------
// Causal depthwise conv (K=4) + optional per-head RMS norm + optional poly.
// ---------------------------------------------------------------------------
__global__ __launch_bounds__(256) void conv_kernel(const float* __restrict__ xin,
                                                   const float* __restrict__ w,
                                                   const float* __restrict__ bias,
                                                   float* __restrict__ out, int mode) {
    int bt = blockIdx.x;
    int t = bt & (T_ - 1);
    int tid = threadIdx.x;
    int c0 = tid * 4;
    float4 w4[4];
    #pragma unroll
    for (int i = 0; i < 4; i++) w4[i] = *(const float4*)&w[(c0 + i) * 4];
    float4 bi = *(const float4*)&bias[c0];
    float4 xs[4];
    #pragma unroll
    for (int j = 0; j < 4; j++) {
        int tt = t - 3 + j;
        xs[j] = (tt >= 0) ? *(const float4*)&xin[(bt - 3 + j) * C_ + c0]
                          : make_float4(0.f, 0.f, 0.f, 0.f);
    }
    float y0 = bi.x + w4[0].x * xs[0].x + w4[0].y * xs[1].x + w4[0].z * xs[2].x + w4[0].w * xs[3].x;
    float y1 = bi.y + w4[1].x * xs[0].y + w4[1].y * xs[1].y + w4[1].z * xs[2].y + w4[1].w * xs[3].y;
    float y2 = bi.z + w4[2].x * xs[0].z + w4[2].y * xs[1].z + w4[2].z * xs[2].z + w4[2].w * xs[3].z;
    float y3 = bi.w + w4[3].x * xs[0].w + w4[3].y * xs[1].w + w4[3].z * xs[2].w + w4[3].w * xs[3].w;
    if (mode >= 1) {
        float ss = y0 * y0 + y1 * y1 + y2 * y2 + y3 * y3;
        ss += __shfl_xor(ss, 1);
        ss += __shfl_xor(ss, 2);
        ss += __shfl_xor(ss, 4);
        ss += __shfl_xor(ss, 8);
        float sc = rsqrtf(ss * (1.f / 64.f) + 1e-6f);
        y0 *= sc; y1 *= sc; y2 *= sc; y3 *= sc;
        if (mode == 2) {
            y0 += 0.5f * y0 * y0; y1 += 0.5f * y1 * y1;
            y2 += 0.5f * y2 * y2; y3 += 0.5f * y3 * y3;
        }
    }
    *(float4*)&out[bt * C_ + c0] = make_float4(y0, y1, y2, y3);
}

// ---------------------------------------------------------------------------
// chunk_s: standalone (chunk 0 only). chunkS f32.
// ---------------------------------------------------------------------------
__global__ __launch_bounds__(256) void chunk_s_kernel(const float* __restrict__ kbuf,
                                                      const float* __restrict__ vbuf,
                                                      const float* __restrict__ gates,
                                                      const float* __restrict__ Mc,
                                                      float* __restrict__ Sc,
                                                      float* __restrict__ chunkS,
                                                      int chunk) {
    __shared__ float Kc[CS_][68];
    __shared__ float Mrow[8][68];
    __shared__ float errS[CS_][8];
    __shared__ float thS[CS_], etS[CS_], gmS[CS_];
    int tid = threadIdx.x;
    int idx = blockIdx.x;
    int vt = idx & 7, h = (idx >> 3) & 15, b = idx >> 7;
    int c0t = chunk * CS_;
    {
        int row = tid >> 2, col = (tid & 3) * 16;
        const float* src = &kbuf[((size_t)(b * T_ + c0t + row) * H_ + h) * D_];
        #pragma unroll
        for (int i = 0; i < 4; i++)
            *(float4*)&Kc[row][col + i * 4] = *(const float4*)&src[col + i * 4];
    }
    if (tid < 128) {
        int v = tid >> 4, cc = (tid & 15) * 4;
        *(float4*)&Mrow[v][cc] =
            *(const float4*)&Mc[((size_t)(b * H_ + h)) * 4096 + (vt * 8 + v) * 64 + cc];
    }
    if (tid < CS_)           thS[tid] = gates[2 * (B_ * T_ * H_) + (b * T_ + c0t + tid) * H_ + h];
    else if (tid < 2 * CS_)  { int t = tid - CS_;     etS[t] = gates[1 * (B_ * T_ * H_) + (b * T_ + c0t + t) * H_ + h]; }
    else if (tid < 3 * CS_)  { int t = tid - 2 * CS_; gmS[t] = gates[3 * (B_ * T_ * H_) + (b * T_ + c0t + t) * H_ + h]; }
    __syncthreads();
    {
        int t = tid >> 2, v0 = (tid & 3) * 2;
        float s0 = 0.f, s1 = 0.f;
        #pragma unroll
        for (int k = 0; k < 64; k += 4) {
            float4 kv = *(float4*)&Kc[t][k];
            float4 m0 = *(float4*)&Mrow[v0][k];
            float4 m1 = *(float4*)&Mrow[v0 + 1][k];
            s0 += kv.x * m0.x + kv.y * m0.y + kv.z * m0.z + kv.w * m0.w;
            s1 += kv.x * m1.x + kv.y * m1.y + kv.z * m1.z + kv.w * m1.w;
        }
        const float* vp = &vbuf[((size_t)(b * T_ + c0t + t) * H_ + h) * D_ + vt * 8 + v0];
        errS[t][v0]     = s0 - vp[0];
        errS[t][v0 + 1] = s1 - vp[1];
    }
    __syncthreads();
    int vl = tid >> 5;
    int kk = (tid & 31) * 2;
    size_t sIdx = ((size_t)(b * H_ + h)) * 4096 + (vt * 8 + vl) * 64 + kk;
    float S0 = Sc[sIdx], S1 = Sc[sIdx + 1];
    float ring0[16] = {}, ring1[16] = {};
    float cum0 = 0.f, cum1 = 0.f;
    for (int cb = 0; cb < 4; ++cb) {
        #pragma unroll
        for (int ci = 0; ci < 16; ++ci) {
            int c = cb * 16 + ci;
            float er = 2.f * errS[c][vl];
            float2 kv = *(float2*)&Kc[c][kk];
            float g = gmS[c];
            cum0 += g * er * kv.x;
            cum1 += g * er * kv.y;
            float uw0 = cum0 - ring0[ci];
            float uw1 = cum1 - ring1[ci];
            ring0[ci] = cum0; ring1[ci] = cum1;
            float th = thS[c], et = etS[c];
            S0 = th * S0 - et * uw0;
            S1 = th * S1 - et * uw1;
            size_t o = ((size_t)((b * H_ + h) * CS_ + c)) * 4096 + (vt * 8 + vl) * 64 + kk;
            *(float2*)&chunkS[o] = make_float2(S0, S1);
        }
    }
    Sc[sIdx] = S0; Sc[sIdx + 1] = S1;
}

// ---------------------------------------------------------------------------
// Polar-Express, QUADRANT ownership, 4-barrier schedule, plain FP16 operands.
// ---------------------------------------------------------------------------
__device__ inline f16x8 ldH(const _Float16* buf, int row, int t, int q) {
    return *(const f16x8*)&buf[row * IST2 + t * 32 + q * 8];
}
__device__ inline void mmQ16(f32x4 (&out)[2][2],
                             const _Float16* bufA, const _Float16* bufB,
                             int ar0, int br0, int c, int q, bool share) {
    f16x8 a[2][2];
    #pragma unroll
    for (int rt = 0; rt < 2; rt++)
        #pragma unroll
        for (int t = 0; t < 2; t++)
            a[rt][t] = ldH(bufA, ar0 + 16 * rt + c, t, q);
    #pragma unroll
    for (int ctl = 0; ctl < 2; ctl++) {
        f16x8 b[2];
        if (share && ar0 == br0) {
            b[0] = a[ctl][0]; b[1] = a[ctl][1];
        } else {
            b[0] = ldH(bufB, br0 + 16 * ctl + c, 0, q);
            b[1] = ldH(bufB, br0 + 16 * ctl + c, 1, q);
        }
        #pragma unroll
        for (int rt = 0; rt < 2; rt++) {
            f32x4 acc = {0.f, 0.f, 0.f, 0.f};
            acc = __builtin_amdgcn_mfma_f32_16x16x32_f16(a[rt][0], b[0], acc, 0, 0, 0);
            acc = __builtin_amdgcn_mfma_f32_16x16x32_f16(a[rt][1], b[1], acc, 0, 0, 0);
            out[rt][ctl] = acc;
        }
    }
}
__device__ inline void writeRowQ16(_Float16* buf, const f32x4 (&M)[2][2],
                                   int ar0, int br0, int q, int c) {
    #pragma unroll
    for (int rt = 0; rt < 2; rt++)
        #pragma unroll
        for (int ctl = 0; ctl < 2; ctl++)
            #pragma unroll
            for (int r = 0; r < 4; r++)
                buf[(ar0 + 16 * rt + 4 * q + r) * IST2 + br0 + 16 * ctl + c] =
                    (_Float16)M[rt][ctl][r];
}
__device__ inline void writeColQ16(_Float16* buf, const f32x4 (&M)[2][2],
                                   int ar0, int br0, int q, int c) {
    #pragma unroll
    for (int rt = 0; rt < 2; rt++)
        #pragma unroll
        for (int ctl = 0; ctl < 2; ctl++) {
            unsigned short d[4];
            #pragma unroll
            for (int r = 0; r < 4; r++)
                d[r] = __builtin_bit_cast(unsigned short, (_Float16)M[rt][ctl][r]);
            *(uint2*)&buf[(br0 + 16 * ctl + c) * IST2 + ar0 + 16 * rt + 4 * q] =
                make_uint2((unsigned)d[0] | ((unsigned)d[1] << 16),
                           (unsigned)d[2] | ((unsigned)d[3] << 16));
        }
}

__global__ __launch_bounds__(256, 5) void polar_kernel(const float* __restrict__ chunkS,
                                                       __half* __restrict__ Z) {
    __shared__ __align__(16) _Float16 Xi[64 * IST2];
    __shared__ __align__(16) _Float16 Xti[64 * IST2];
    __shared__ __align__(16) _Float16 Yi[64 * IST2];
    __shared__ float red[4];
    int tid = threadIdx.x;
    int w = tid >> 6, lane = tid & 63;
    int q = lane >> 4, c = lane & 15;
    int ar0 = (w >> 1) * 32, br0 = (w & 1) * 32;
    size_t base = (size_t)blockIdx.x * 4096;

    f32x4 Xc[2][2];
    float ss = 0.f;
    #pragma unroll
    for (int rt = 0; rt < 2; rt++)
        #pragma unroll
        for (int ctl = 0; ctl < 2; ctl++)
            #pragma unroll
            for (int r = 0; r < 4; r++) {
                float v = chunkS[base + (size_t)(ar0 + 16 * rt + 4 * q + r) * 64 + br0 + 16 * ctl + c];
                Xc[rt][ctl][r] = v;
                ss += v * v;
            }
    ss += __shfl_xor(ss, 1);  ss += __shfl_xor(ss, 2);  ss += __shfl_xor(ss, 4);
    ss += __shfl_xor(ss, 8);  ss += __shfl_xor(ss, 16); ss += __shfl_xor(ss, 32);
    if (lane == 0) red[w] = ss;
    __syncthreads();
    float sc = 1.f / (sqrtf(red[0] + red[1] + red[2] + red[3]) + 1e-7f);
    #pragma unroll
    for (int rt = 0; rt < 2; rt++)
        #pragma unroll
        for (int ctl = 0; ctl < 2; ctl++)
            #pragma unroll
            for (int r = 0; r < 4; r++) Xc[rt][ctl][r] *= sc;
    writeRowQ16(Xi, Xc, ar0, br0, q, c);
    writeColQ16(Xti, Xc, ar0, br0, q, c);
    __syncthreads();

    const float na = 3.4445f, nb = -4.7750f, ncf = 2.0315f;
    f32x4 Yc[2][2], Tc[2][2];
    for (int it = 0; it < NS_; ++it) {
        mmQ16(Yc, Xi, Xi, ar0, br0, c, q, true);
        writeRowQ16(Yi, Yc, ar0, br0, q, c);
        __syncthreads();   // b1
        mmQ16(Tc, Yi, Yi, ar0, br0, c, q, true);
        #pragma unroll
        for (int rt = 0; rt < 2; rt++)
            #pragma unroll
            for (int ctl = 0; ctl < 2; ctl++)
                #pragma unroll
                for (int r = 0; r < 4; r++)
                    Yc[rt][ctl][r] = nb * Yc[rt][ctl][r] + ncf * Tc[rt][ctl][r];
        __syncthreads();   // b2
        writeRowQ16(Yi, Yc, ar0, br0, q, c);
        __syncthreads();   // b3
        mmQ16(Tc, Yi, Xti, ar0, br0, c, q, false);
        #pragma unroll
        for (int rt = 0; rt < 2; rt++)
            #pragma unroll
            for (int ctl = 0; ctl < 2; ctl++)
                #pragma unroll
                for (int r = 0; r < 4; r++)
                    Xc[rt][ctl][r] = na * Xc[rt][ctl][r] + Tc[rt][ctl][r];
        if (it != NS_ - 1) {
            writeRowQ16(Xi, Xc, ar0, br0, q, c);
            __syncthreads();                       // b4
            writeColQ16(Xti, Xc, ar0, br0, q, c);
        }
    }
    #pragma unroll
    for (int rt = 0; rt < 2; rt++)
        #pragma unroll
        for (int ctl = 0; ctl < 2; ctl++)
            #pragma unroll
            for (int r = 0; r < 4; r++)
                Z[base + (size_t)(ar0 + 16 * rt + 4 * q + r) * 64 + br0 + 16 * ctl + c] =
                    __float2half(Xc[rt][ctl][r]);
}

// ---------------------------------------------------------------------------
// Fused: m_y(ch) + chunk_s(ch+1). 512 blocks (vt 0..15, 4 v-rows each) for
// 2 blocks/CU memory parallelism; 8-deep Zb prefetch ring; chunkS f32.
// Each thread owns ONE (v,k) element; each wave = one v-row (64 k lanes).
// ---------------------------------------------------------------------------
__global__ __launch_bounds__(256) void fused_my_cs(const __half* __restrict__ Zb,
                                                   const float* __restrict__ qbuf,
                                                   const float* __restrict__ kbuf,
                                                   const float* __restrict__ vbuf,
                                                   const float* __restrict__ gates,
                                                   float* __restrict__ Mc,
                                                   float* __restrict__ Sc,
                                                   float* __restrict__ chunkS,
                                                   float* __restrict__ ybuf,
                                                   int chunk) {
    __shared__ float buf[CS_][68];
    __shared__ float Mrow[4][68];
    __shared__ float errS[CS_][4];
    __shared__ float alS[CS_], thS[CS_], etS[CS_], gmS[CS_];
    int tid = threadIdx.x, idx = blockIdx.x;
    int vt = idx & 15, h = (idx >> 4) & 15, b = idx >> 8;
    int c0t = chunk * CS_;
    {
        int row = tid >> 2, col = (tid & 3) * 16;
        const float* src = &qbuf[((size_t)(b * T_ + c0t + row) * H_ + h) * D_];
        #pragma unroll
        for (int i = 0; i < 4; i++)
            *(float4*)&buf[row][col + i * 4] = *(const float4*)&src[col + i * 4];
    }
    if (tid < CS_) alS[tid] = gates[0 * (B_ * T_ * H_) + (b * T_ + c0t + tid) * H_ + h];
    __syncthreads();
    int vl = tid >> 6, k0 = tid & 63;
    size_t mIdx = ((size_t)(b * H_ + h)) * 4096 + (vt * 4 + vl) * 64 + k0;
    size_t zrow = ((size_t)(b * H_ + h) * CS_) * 4096 + (vt * 4 + vl) * 64 + k0;
    float M0 = Mc[mIdx];
    // 8-deep register prefetch ring for Zb (scalar half per thread)
    unsigned short zr[8];
    #pragma unroll
    for (int j = 0; j < 8; j++)
        zr[j] = *(const unsigned short*)&Zb[zrow + (size_t)j * 4096];
    #pragma unroll
    for (int c = 0; c < CS_; c++) {
        float z = __half2float(__builtin_bit_cast(__half, zr[c & 7]));
        if (c + 8 < CS_)
            zr[c & 7] = *(const unsigned short*)&Zb[zrow + (size_t)(c + 8) * 4096];
        float al = alS[c];
        M0 = al * M0 + z;
        float p = M0 * buf[c][k0];
        p += __shfl_xor(p, 1);  p += __shfl_xor(p, 2);  p += __shfl_xor(p, 4);
        p += __shfl_xor(p, 8);  p += __shfl_xor(p, 16); p += __shfl_xor(p, 32);
        if ((tid & 63) == 0)
            ybuf[((size_t)(b * T_ + c0t + c) * H_ + h) * D_ + vt * 4 + vl] = p;
    }
    Mc[mIdx] = M0;
    if (chunk + 1 >= NC_) return;
    int c1t = c0t + CS_;
    __syncthreads();
    Mrow[vl][k0] = M0;
    {
        int row = tid >> 2, col = (tid & 3) * 16;
        const float* src = &kbuf[((size_t)(b * T_ + c1t + row) * H_ + h) * D_];
        #pragma unroll
        for (int i = 0; i < 4; i++)
            *(float4*)&buf[row][col + i * 4] = *(const float4*)&src[col + i * 4];
    }
    if (tid < CS_)           thS[tid] = gates[2 * (B_ * T_ * H_) + (b * T_ + c1t + tid) * H_ + h];
    else if (tid < 2 * CS_)  { int t = tid - CS_;     etS[t] = gates[1 * (B_ * T_ * H_) + (b * T_ + c1t + t) * H_ + h]; }
    else if (tid < 3 * CS_)  { int t = tid - 2 * CS_; gmS[t] = gates[3 * (B_ * T_ * H_) + (b * T_ + c1t + t) * H_ + h]; }
    __syncthreads();
    {
        int t = tid >> 2, v0 = tid & 3;
        float s0 = 0.f;
        #pragma unroll
        for (int k = 0; k < 64; k += 4) {
            float4 kv = *(float4*)&buf[t][k];
            float4 mv = *(float4*)&Mrow[v0][k];
            s0 += kv.x * mv.x + kv.y * mv.y + kv.z * mv.z + kv.w * mv.w;
        }
        const float* vp = &vbuf[((size_t)(b * T_ + c1t + t) * H_ + h) * D_ + vt * 4 + v0];
        errS[t][v0] = s0 - vp[0];
    }
    __syncthreads();
    float S0 = Sc[mIdx];
    float ring0[16] = {};
    float cum0 = 0.f;
    for (int cb = 0; cb < 4; ++cb) {
        #pragma unroll
        for (int ci = 0; ci < 16; ++ci) {
            int cc = cb * 16 + ci;
            float er = 2.f * errS[cc][vl];
            float kv = buf[cc][k0];
            float g = gmS[cc];
            cum0 += g * er * kv;
            float uw0 = cum0 - ring0[ci];
            ring0[ci] = cum0;
            float th = thS[cc], et = etS[cc];
            S0 = th * S0 - et * uw0;
            chunkS[((size_t)((b * H_ + h) * CS_ + cc)) * 4096 + (vt * 4 + vl) * 64 + k0] = S0;
        }
    }
    Sc[mIdx] = S0;
}

// ---------------------------------------------------------------------------
extern "C" void kernel_launch(void* const* d_in, const int* in_sizes, int n_in,
                              void* d_out, int out_size, void* d_ws, size_t ws_size,
                              hipStream_t stream) {
    (void)in_sizes; (void)n_in; (void)out_size; (void)ws_size;
    const float* x     = (const float*)d_in[0];
    const float* Wq    = (const float*)d_in[1];
    const float* Wk    = (const float*)d_in[2];
    const float* Wv    = (const float*)d_in[3];
    const float* Wproj = (const float*)d_in[4];
    const float* cqw   = (const float*)d_in[5];
    const float* cqb   = (const float*)d_in[6];
    const float* ckw   = (const float*)d_in[7];
    const float* ckb   = (const float*)d_in[8];
    const float* cvw   = (const float*)d_in[9];
    const float* cvb   = (const float*)d_in[10];
    const float* Wa    = (const float*)d_in[11];
    const float* We    = (const float*)d_in[12];
    const float* Wt    = (const float*)d_in[13];
    const float* Wg    = (const float*)d_in[14];

    float* ws  = (float*)d_ws;
    float* Qb  = ws;                      // 4194304 floats (B,T,C)
    float* Kb  = Qb + 4194304;
    float* Vb  = Kb + 4194304;
    float* Yb  = Vb + 4194304;
    float* Gb  = Yb + 4194304;            // 262144 (4,B,T,H)
    float* Mc  = Gb + 262144;             // 131072 (B,H,D,D)
    float* Sc  = Mc + 131072;             // 131072
    float* CSb = Sc + 131072;             // 8388608-float region (f32 chunkS)
    float* Zr  = CSb + 8388608;           // 8388608-float region
    __half* Zh = (__half*)Zr;             // fp16 Z (first half)
    float* bufA = Zr + 4194304;           // gemm scratch (disjoint second half)
    // fp16 GEMM operand buffers alias CSb (dead once chunk loop starts)
    _Float16* su = (_Float16*)CSb;
    _Float16* xH  = su;                   // 4194304 halves
    _Float16* WqH = su + 4194304;         // 1048576 halves each
    _Float16* WkH = su + 5242880;
    _Float16* WvH = su + 6291456;
    _Float16* WgH = su + 7340032;         // 65536 halves (gates W, 64x1024)

    hipMemsetAsync(Mc, 0, 2 * 131072 * sizeof(float), stream);

    split16_kernel<<<2048, 256, 0, stream>>>(x, xH, 4194304);
    split16_kernel<<<512, 256, 0, stream>>>(Wq, WqH, 1048576);
    split16_kernel<<<512, 256, 0, stream>>>(Wk, WkH, 1048576);
    split16_kernel<<<512, 256, 0, stream>>>(Wv, WvH, 1048576);
    split16_kernel<<<8, 256, 0, stream>>>(Wa, WgH, 16384);
    split16_kernel<<<8, 256, 0, stream>>>(We, WgH + 16384, 16384);
    split16_kernel<<<8, 256, 0, stream>>>(Wt, WgH + 32768, 16384);
    split16_kernel<<<8, 256, 0, stream>>>(Wg, WgH + 49152, 16384);

    dim3 gs(C_ / 128, (B_ * T_) / 128);
    gemm16<<<gs, 256, 0, stream>>>(xH, WqH, bufA);
    conv_kernel<<<B_ * T_, 256, 0, stream>>>(bufA, cqw, cqb, Qb, 1);
    gemm16<<<gs, 256, 0, stream>>>(xH, WkH, bufA);
    conv_kernel<<<B_ * T_, 256, 0, stream>>>(bufA, ckw, ckb, Kb, 2);
    gemm16<<<gs, 256, 0, stream>>>(xH, WvH, bufA);
    conv_kernel<<<B_ * T_, 256, 0, stream>>>(bufA, cvw, cvb, Vb, 0);
    gates16<<<(B_ * T_) / 64, 256, 0, stream>>>(xH, WgH, Gb);

    chunk_s_kernel<<<B_ * H_ * 8, 256, 0, stream>>>(Kb, Vb, Gb, Mc, Sc, CSb, 0);
    for (int ch = 0; ch < NC_; ++ch) {
        polar_kernel<<<B_ * H_ * CS_, 256, 0, stream>>>(CSb, Zh);
        fused_my_cs<<<B_ * H_ * 16, 256, 0, stream>>>(Zh, Qb, Kb, Vb, Gb, Mc, Sc, CSb, Yb, ch);
    }

    _Float16* YbH = su;
    _Float16* WpH = su + 4194304;
    split16_kernel<<<2048, 256, 0, stream>>>(Yb, YbH, 4194304);
    split16_kernel<<<512, 256, 0, stream>>>(Wproj, WpH, 1048576);
    gemm16<<<gs, 256, 0, stream>>>(YbH, WpH, (float*)d_out);
}